// Round 2
// baseline (1573.269 us; speedup 1.0000x reference)
//
#include <hip/hip_runtime.h>
#include <hip/hip_bf16.h>

// GraphConvNet on MI355X — round 1: bf16-MFMA fused MLP2 kernels.
// Round-1 changes vs round 0 (crash = suspected d_ws overflow at 333 MB):
//   * eh state stored as bf16 (128 MB, was 256 MB fp32)
//   * single nh buffer, in-place node update (saves 25.6 MB)
//   * ws_size guard: early-return instead of OOB write (clean diagnostic)
//   * zero-fill kernel instead of hipMemsetAsync
// Total ws footprint now ~180 MB.
//
// MFMA fragment facts (guide §3, m89/m91/m120 verified):
//   A: lane holds A[m=lane&15][k=(lane>>4)*8+j]
//   B: lane holds B[k=(lane>>4)*8+j][n=lane&15]
//   C/D: lane reg r holds C[row=(lane>>4)*4+r][col=lane&15]

typedef __bf16 bf16;
typedef __attribute__((ext_vector_type(8))) __bf16 bf16x8;
typedef __attribute__((ext_vector_type(4))) __bf16 bf16x4;
typedef __attribute__((ext_vector_type(4))) float f32x4;

__device__ __forceinline__ float gelu_t(float x) {
    // jax.nn.gelu(approximate=True)
    const float c0 = 0.7978845608028654f;
    float u = c0 * (x + 0.044715f * x * x * x);
    float au = fabsf(u);
    float e = __expf(-2.0f * au);
    float t = (1.0f - e) / (1.0f + e);
    t = (u < 0.0f) ? -t : t;
    return 0.5f * x * (1.0f + t);
}

__device__ __forceinline__ void st_bf4(bf16* p, float4 v) {
    bf16x4 o;
    o.x = (bf16)v.x; o.y = (bf16)v.y; o.z = (bf16)v.z; o.w = (bf16)v.w;
    *(bf16x4*)p = o;
}

// ---------------- weight packing: [K,128] fp32 -> bf16 [K/8][128][8] ----------------
struct PackDesc { const float* src; int Kcopy; int dstOff; };
struct PackArgs { PackDesc d[13]; };

__global__ __launch_bounds__(256) void pack_all_kernel(PackArgs pa, bf16* dst, int total) {
    int i = blockIdx.x * 256 + threadIdx.x;
    if (i >= total) return;
    int s = 0;
#pragma unroll
    for (int j = 1; j < 13; ++j) if (i >= pa.d[j].dstOff) s = j;
    int local = i - pa.d[s].dstOff;
    int k = local >> 7, n = local & 127;
    float v = (k < pa.d[s].Kcopy) ? pa.d[s].src[(size_t)k * 128 + n] : 0.0f;
    dst[pa.d[s].dstOff + ((k >> 3) * 128 + n) * 8 + (k & 7)] = (bf16)v;
}

__global__ void fold_bias_kernel(const float* g, const float* euW0, const float* eub0,
                                 const float* nuW0, const float* nub0,
                                 float* eu_eff, float* nu_eff) {
    int t = threadIdx.x;
    if (t < 128) {
        float g0 = g[0], g1 = g[1];
#pragma unroll
        for (int s = 0; s < 2; ++s) {
            eu_eff[s * 128 + t] = eub0[s * 128 + t]
                + g0 * euW0[((size_t)s * 386 + 384) * 128 + t]
                + g1 * euW0[((size_t)s * 386 + 385) * 128 + t];
            nu_eff[s * 128 + t] = nub0[s * 128 + t]
                + g0 * nuW0[((size_t)s * 258 + 256) * 128 + t]
                + g1 * nuW0[((size_t)s * 258 + 257) * 128 + t];
        }
    }
}

__global__ __launch_bounds__(256) void zero_kernel(float4* p, int n4) {
    int i = blockIdx.x * 256 + threadIdx.x;
    if (i < n4) p[i] = float4{0.0f, 0.0f, 0.0f, 0.0f};
}

// ---------------- fused MLP2 ----------------
// MODE 0: embed nodes  (K1=32, raw 7)  fp32 in  -> fp32 nh
// MODE 1: embed edges  (K1=32, raw 3)  fp32 in  -> bf16 eh
// MODE 2: edge update  (K1=384) bf16 eh + fp32 nh gather -> bf16 eh in-place,
//         atomicAdd fp32 recv, skip+LN
// MODE 3: node update  (K1=256) fp32 nh + fp32 recv -> fp32 nh in-place, skip+LN
// MODE 4: decode GEMM1 only -> fp32 hid (gelu'd)
template <int MODE, int K1, int RAWF>
__global__ __launch_bounds__(256) void mlp2_kernel(
    const void* __restrict__ Araw0v, const float* __restrict__ Araw1,
    const int* __restrict__ senders, const int* __restrict__ receivers,
    const bf16* __restrict__ W0p, const float* __restrict__ b0,
    const bf16* __restrict__ W1p, const float* __restrict__ b1,
    const float* __restrict__ ln_s, const float* __restrict__ ln_b,
    void* out0v, float* recv_out, int Mtotal)
{
    constexpr int KP = K1 + 8;  // +16B pad: row stride stays 16B-aligned, 2-way bank alias (free)
    __shared__ __align__(16) bf16 A[64][KP];
    __shared__ __align__(16) bf16 Hsep[(K1 == 32) ? (4 * 16 * 136) : 1];
    __shared__ int sI[64], rI[64];

    const int tid = threadIdx.x;
    const int m0 = blockIdx.x * 64;

    const float* Araw0f = (const float*)Araw0v;
    const bf16*  Araw0b = (const bf16*)Araw0v;
    float* out0f = (float*)out0v;
    bf16*  out0b = (bf16*)out0v;

    if constexpr (MODE == 2) {
        if (tid < 64) {
            int e = m0 + tid; if (e >= Mtotal) e = Mtotal - 1;
            sI[tid] = senders[e]; rI[tid] = receivers[e];
        }
        __syncthreads();
    }

    // ---- stage A tile (bf16) ----
    if constexpr (MODE == 2) {
        for (int i = tid; i < 64 * 16; i += 256) {          // eh rows: direct bf16x8 copy
            int r = i >> 4, c = (i & 15) << 3;
            int row = m0 + r; if (row >= Mtotal) row = Mtotal - 1;
            *(bf16x8*)&A[r][c] = *(const bf16x8*)(Araw0b + (size_t)row * 128 + c);
        }
        for (int i = tid; i < 64 * 32; i += 256) {          // nh gather: float4 -> bf16x4
            int r = i >> 5, c = (i & 31) << 2;
            float4 v1 = *(const float4*)(Araw1 + (size_t)sI[r] * 128 + c);
            float4 v2 = *(const float4*)(Araw1 + (size_t)rI[r] * 128 + c);
            st_bf4(&A[r][128 + c], v1); st_bf4(&A[r][256 + c], v2);
        }
    } else if constexpr (MODE == 3) {
        for (int i = tid; i < 64 * 32; i += 256) {
            int r = i >> 5, c = (i & 31) << 2;
            int row = m0 + r; if (row >= Mtotal) row = Mtotal - 1;
            st_bf4(&A[r][c], *(const float4*)(Araw0f + (size_t)row * 128 + c));
            st_bf4(&A[r][128 + c], *(const float4*)(Araw1 + (size_t)row * 128 + c));
        }
    } else if constexpr (MODE == 4) {
        for (int i = tid; i < 64 * 32; i += 256) {
            int r = i >> 5, c = (i & 31) << 2;
            int row = m0 + r; if (row >= Mtotal) row = Mtotal - 1;
            st_bf4(&A[r][c], *(const float4*)(Araw0f + (size_t)row * 128 + c));
        }
    } else {  // embeds: RAWF raw features, zero-pad to 32
        for (int i = tid; i < 64 * 32; i += 256) {
            int r = i >> 5, c = i & 31;
            int row = m0 + r; if (row >= Mtotal) row = Mtotal - 1;
            A[r][c] = (c < RAWF) ? (bf16)Araw0f[(size_t)row * RAWF + c] : (bf16)0.0f;
        }
    }
    __syncthreads();

    const int lane = tid & 63;
    const int w = tid >> 6;
    const int n16 = lane & 15;
    const int quad = lane >> 4;

    const f32x4 z = {0.0f, 0.0f, 0.0f, 0.0f};
    f32x4 acc[8];
#pragma unroll
    for (int t = 0; t < 8; ++t) acc[t] = z;

    // ---- GEMM1: [64,K1] @ [K1,128] ----
#pragma unroll
    for (int kc = 0; kc < K1; kc += 32) {
        bf16x8 a = *(const bf16x8*)&A[w * 16 + n16][kc + quad * 8];
        const bf16* bp = W0p + ((size_t)(((kc >> 3) + quad) * 128 + n16)) * 8;
#pragma unroll
        for (int t = 0; t < 8; ++t) {
            bf16x8 b = *(const bf16x8*)(bp + t * 128);
            acc[t] = __builtin_amdgcn_mfma_f32_16x16x32_bf16(a, b, acc[t], 0, 0, 0);
        }
    }

    float b0v[8];
#pragma unroll
    for (int t = 0; t < 8; ++t) b0v[t] = b0[t * 16 + n16];

    if constexpr (MODE == 4) {  // decode layer 1 only
#pragma unroll
        for (int t = 0; t < 8; ++t)
#pragma unroll
            for (int r = 0; r < 4; ++r) {
                int row = m0 + w * 16 + quad * 4 + r;
                if (row < Mtotal)
                    out0f[(size_t)row * 128 + t * 16 + n16] = gelu_t(acc[t][r] + b0v[t]);
            }
        return;
    }

    // hidden -> A-operand layout via LDS (wave-private slab; A rows dead after GEMM1)
    bf16* Hw = (K1 == 32) ? &Hsep[w * 16 * 136] : &A[w * 16][0];
#pragma unroll
    for (int t = 0; t < 8; ++t)
#pragma unroll
        for (int r = 0; r < 4; ++r)
            Hw[(quad * 4 + r) * 136 + t * 16 + n16] = (bf16)gelu_t(acc[t][r] + b0v[t]);

    f32x4 acc2[8];
#pragma unroll
    for (int t = 0; t < 8; ++t) acc2[t] = z;

    // ---- GEMM2: [64,128] @ [128,128] ----
#pragma unroll
    for (int kc = 0; kc < 128; kc += 32) {
        bf16x8 a = *(const bf16x8*)&Hw[n16 * 136 + kc + quad * 8];
        const bf16* bp = W1p + ((size_t)(((kc >> 3) + quad) * 128 + n16)) * 8;
#pragma unroll
        for (int t = 0; t < 8; ++t) {
            bf16x8 b = *(const bf16x8*)(bp + t * 128);
            acc2[t] = __builtin_amdgcn_mfma_f32_16x16x32_bf16(a, b, acc2[t], 0, 0, 0);
        }
    }

    if constexpr (MODE == 0 || MODE == 1) {  // embed: plain store
#pragma unroll
        for (int t = 0; t < 8; ++t) {
            float b1v = b1[t * 16 + n16];
#pragma unroll
            for (int r = 0; r < 4; ++r) {
                int row = m0 + w * 16 + quad * 4 + r;
                if (row < Mtotal) {
                    float v = acc2[t][r] + b1v;
                    if constexpr (MODE == 0) out0f[(size_t)row * 128 + t * 16 + n16] = v;
                    else                     out0b[(size_t)row * 128 + t * 16 + n16] = (bf16)v;
                }
            }
        }
        return;
    }

    // ---- MODE 2/3 epilogue: (atomic scatter) + skip + LayerNorm ----
    float b1v[8], scl[8], bia[8];
#pragma unroll
    for (int t = 0; t < 8; ++t) {
        int col = t * 16 + n16;
        b1v[t] = b1[col]; scl[t] = ln_s[col]; bia[t] = ln_b[col];
    }
    int rowg[4], rcv4[4];
#pragma unroll
    for (int r = 0; r < 4; ++r) {
        int rr = w * 16 + quad * 4 + r;
        rowg[r] = m0 + rr;
        if constexpr (MODE == 2) rcv4[r] = rI[rr];
    }
    float x[8][4];
    float sm[4] = {0, 0, 0, 0}, sq[4] = {0, 0, 0, 0};
#pragma unroll
    for (int t = 0; t < 8; ++t) {
        int col = t * 16 + n16;
#pragma unroll
        for (int r = 0; r < 4; ++r) {
            float v = acc2[t][r] + b1v[t];
            bool ok = rowg[r] < Mtotal;
            float old;
            if constexpr (MODE == 2) {
                if (ok) unsafeAtomicAdd(recv_out + (size_t)rcv4[r] * 128 + col, v);
                old = ok ? (float)Araw0b[(size_t)rowg[r] * 128 + col] : 0.0f;
            } else {
                old = ok ? Araw0f[(size_t)rowg[r] * 128 + col] : 0.0f;
            }
            float xx = old + v;
            x[t][r] = xx; sm[r] += xx; sq[r] += xx * xx;
        }
    }
    // row lives entirely in this 16-lane quad: butterfly over masks 1,2,4,8
#pragma unroll
    for (int m = 1; m < 16; m <<= 1) {
#pragma unroll
        for (int r = 0; r < 4; ++r) {
            sm[r] += __shfl_xor(sm[r], m);
            sq[r] += __shfl_xor(sq[r], m);
        }
    }
    float mean[4], inv[4];
#pragma unroll
    for (int r = 0; r < 4; ++r) {
        mean[r] = sm[r] * (1.0f / 128.0f);
        float var = sq[r] * (1.0f / 128.0f) - mean[r] * mean[r];
        inv[r] = rsqrtf(var + 1e-6f);
    }
#pragma unroll
    for (int t = 0; t < 8; ++t)
#pragma unroll
        for (int r = 0; r < 4; ++r)
            if (rowg[r] < Mtotal) {
                float v = (x[t][r] - mean[r]) * inv[r] * scl[t] + bia[t];
                if constexpr (MODE == 2) out0b[(size_t)rowg[r] * 128 + t * 16 + n16] = (bf16)v;
                else                     out0f[(size_t)rowg[r] * 128 + t * 16 + n16] = v;
            }
}

// ---------------- decoder layer 2: [N,128]@[128,3] ----------------
__global__ __launch_bounds__(256) void decode2_kernel(
    const float* __restrict__ hid, const float* __restrict__ W1,
    const float* __restrict__ b1, float* __restrict__ out, int n)
{
    int gid = blockIdx.x * 256 + threadIdx.x;
    if (gid >= n * 3) return;
    int node = gid / 3, o = gid - node * 3;
    const float* h = hid + (size_t)node * 128;
    float s = b1[o];
#pragma unroll 8
    for (int k = 0; k < 128; ++k) s += h[k] * W1[k * 3 + o];
    out[gid] = s;
}

extern "C" void kernel_launch(void* const* d_in, const int* in_sizes, int n_in,
                              void* d_out, int out_size, void* d_ws, size_t ws_size,
                              hipStream_t stream) {
    const float* nodes   = (const float*)d_in[0];
    const float* edges   = (const float*)d_in[1];
    const float* glob    = (const float*)d_in[2];
    const int*   senders = (const int*)d_in[3];
    const int*   recvrs  = (const int*)d_in[4];
    const float* ne_W0 = (const float*)d_in[5],  *ne_b0 = (const float*)d_in[6];
    const float* ne_W1 = (const float*)d_in[7],  *ne_b1 = (const float*)d_in[8];
    const float* ee_W0 = (const float*)d_in[9],  *ee_b0 = (const float*)d_in[10];
    const float* ee_W1 = (const float*)d_in[11], *ee_b1 = (const float*)d_in[12];
    const float* eu_W0 = (const float*)d_in[13], *eu_b0 = (const float*)d_in[14];
    const float* eu_W1 = (const float*)d_in[15], *eu_b1 = (const float*)d_in[16];
    const float* nu_W0 = (const float*)d_in[17], *nu_b0 = (const float*)d_in[18];
    const float* nu_W1 = (const float*)d_in[19], *nu_b1 = (const float*)d_in[20];
    const float* ln_s  = (const float*)d_in[21], *ln_b  = (const float*)d_in[22];
    const float* dc_W0 = (const float*)d_in[23], *dc_b0 = (const float*)d_in[24];
    const float* dc_W1 = (const float*)d_in[25], *dc_b1 = (const float*)d_in[26];

    const int N = 50000, E = 500000;

    const int KD[13] = {32, 128, 32, 128, 384, 384, 128, 128, 256, 256, 128, 128, 128};
    const int KC[13] = {7, 128, 3, 128, 384, 384, 128, 128, 256, 256, 128, 128, 128};
    int pre[14]; pre[0] = 0;
    for (int i = 0; i < 13; ++i) pre[i + 1] = pre[i] + KD[i] * 128;
    const int totalPack = pre[13];  // 286720 elems

    char* ws = (char*)d_ws;
    size_t off = 0;
    auto alloc = [&](size_t bytes) -> char* {
        char* p = ws + off;
        off = (off + bytes + 255) & ~(size_t)255;
        return p;
    };
    bf16*  Wp     = (bf16*)alloc((size_t)totalPack * 2);
    float* b0e_eu = (float*)alloc(2 * 128 * 4);
    float* b0e_nu = (float*)alloc(2 * 128 * 4);
    float* nh     = (float*)alloc((size_t)N * 128 * 4);
    float* recvb  = (float*)alloc((size_t)N * 128 * 4);
    bf16*  eh     = (bf16*)alloc((size_t)E * 128 * 2);
    float* hid    = recvb;  // reuse: received dead after last node update

    // Guard: if the harness workspace is smaller than our footprint, bail out
    // cleanly (absmax-fail diagnostic) instead of faulting.
    if (off > ws_size) return;

    PackArgs pa;
    const float* srcs[13] = {
        ne_W0, ne_W1, ee_W0, ee_W1,
        eu_W0, eu_W0 + (size_t)386 * 128,
        eu_W1, eu_W1 + (size_t)128 * 128,
        nu_W0, nu_W0 + (size_t)258 * 128,
        nu_W1, nu_W1 + (size_t)128 * 128,
        dc_W0};
    for (int i = 0; i < 13; ++i) { pa.d[i].src = srcs[i]; pa.d[i].Kcopy = KC[i]; pa.d[i].dstOff = pre[i]; }

    pack_all_kernel<<<(totalPack + 255) / 256, 256, 0, stream>>>(pa, Wp, totalPack);
    fold_bias_kernel<<<1, 128, 0, stream>>>(glob, eu_W0, eu_b0, nu_W0, nu_b0, b0e_eu, b0e_nu);

    const int gN = (N + 63) / 64, gE = (E + 63) / 64;
    mlp2_kernel<0, 32, 7><<<gN, 256, 0, stream>>>(
        nodes, nullptr, nullptr, nullptr, Wp + pre[0], ne_b0, Wp + pre[1], ne_b1,
        nullptr, nullptr, nh, nullptr, N);
    mlp2_kernel<1, 32, 3><<<gE, 256, 0, stream>>>(
        edges, nullptr, nullptr, nullptr, Wp + pre[2], ee_b0, Wp + pre[3], ee_b1,
        nullptr, nullptr, eh, nullptr, E);

    const int n4 = N * 128 / 4;
    for (int s = 0; s < 2; ++s) {
        zero_kernel<<<(n4 + 255) / 256, 256, 0, stream>>>((float4*)recvb, n4);
        mlp2_kernel<2, 384, 0><<<gE, 256, 0, stream>>>(
            eh, nh, senders, recvrs, Wp + pre[4 + s], b0e_eu + s * 128,
            Wp + pre[6 + s], eu_b1 + s * 128, ln_s, ln_b, eh, recvb, E);
        mlp2_kernel<3, 256, 0><<<gN, 256, 0, stream>>>(
            nh, recvb, nullptr, nullptr, Wp + pre[8 + s], b0e_nu + s * 128,
            Wp + pre[10 + s], nu_b1 + s * 128, ln_s, ln_b, nh, nullptr, N);
    }

    mlp2_kernel<4, 128, 0><<<gN, 256, 0, stream>>>(
        nh, nullptr, nullptr, nullptr, Wp + pre[12], dc_b0, nullptr, nullptr,
        nullptr, nullptr, hid, nullptr, N);
    decode2_kernel<<<(N * 3 + 255) / 256, 256, 0, stream>>>(hid, dc_W1, dc_b1, (float*)d_out, N);
}

// Round 3
// 1455.678 us; speedup vs baseline: 1.0808x; 1.0808x over previous
//
#include <hip/hip_runtime.h>
#include <hip/hip_bf16.h>

// GraphConvNet on MI355X — round 2: barrier-free direct-from-global A-fragments.
// Round-2 changes vs round 1 (MODE2 was 628 us, 79% stall, occupancy 34%):
//   * A-tile LDS staging REMOVED: each lane loads its MFMA A-fragment straight
//     from global (bf16x8 for eh, float4x2+cvt for nh/recv). Kernel is now
//     barrier-free; LDS 50.7 KB -> 17.4 KB (wave-private H slab only).
//   * receiver indices for epilogue via __shfl (no LDS, no barrier)
//   * embeds (MODE 0/1) load raw features directly (quad 0 only, K<8)
//   * atomics kept — A/B test: if MODE2 still >450 us, round 3 = CSR sort.
//
// MFMA fragment facts (guide §3, m89/m91/m120 verified):
//   A: lane holds A[m=lane&15][k=(lane>>4)*8+j]
//   B: lane holds B[k=(lane>>4)*8+j][n=lane&15]
//   C/D: lane reg r holds C[row=(lane>>4)*4+r][col=lane&15]

typedef __bf16 bf16;
typedef __attribute__((ext_vector_type(8))) __bf16 bf16x8;
typedef __attribute__((ext_vector_type(4))) __bf16 bf16x4;
typedef __attribute__((ext_vector_type(4))) float f32x4;

__device__ __forceinline__ float gelu_t(float x) {
    // jax.nn.gelu(approximate=True)
    const float c0 = 0.7978845608028654f;
    float u = c0 * (x + 0.044715f * x * x * x);
    float au = fabsf(u);
    float e = __expf(-2.0f * au);
    float t = (1.0f - e) / (1.0f + e);
    t = (u < 0.0f) ? -t : t;
    return 0.5f * x * (1.0f + t);
}

__device__ __forceinline__ bf16x8 cvt8(const float* __restrict__ p) {
    float4 v0 = *(const float4*)p;
    float4 v1 = *(const float4*)(p + 4);
    bf16x8 a;
    a[0] = (bf16)v0.x; a[1] = (bf16)v0.y; a[2] = (bf16)v0.z; a[3] = (bf16)v0.w;
    a[4] = (bf16)v1.x; a[5] = (bf16)v1.y; a[6] = (bf16)v1.z; a[7] = (bf16)v1.w;
    return a;
}

// ---------------- weight packing: [K,128] fp32 -> bf16 [K/8][128][8] ----------------
struct PackDesc { const float* src; int Kcopy; int dstOff; };
struct PackArgs { PackDesc d[13]; };

__global__ __launch_bounds__(256) void pack_all_kernel(PackArgs pa, bf16* dst, int total) {
    int i = blockIdx.x * 256 + threadIdx.x;
    if (i >= total) return;
    int s = 0;
#pragma unroll
    for (int j = 1; j < 13; ++j) if (i >= pa.d[j].dstOff) s = j;
    int local = i - pa.d[s].dstOff;
    int k = local >> 7, n = local & 127;
    float v = (k < pa.d[s].Kcopy) ? pa.d[s].src[(size_t)k * 128 + n] : 0.0f;
    dst[pa.d[s].dstOff + ((k >> 3) * 128 + n) * 8 + (k & 7)] = (bf16)v;
}

__global__ void fold_bias_kernel(const float* g, const float* euW0, const float* eub0,
                                 const float* nuW0, const float* nub0,
                                 float* eu_eff, float* nu_eff) {
    int t = threadIdx.x;
    if (t < 128) {
        float g0 = g[0], g1 = g[1];
#pragma unroll
        for (int s = 0; s < 2; ++s) {
            eu_eff[s * 128 + t] = eub0[s * 128 + t]
                + g0 * euW0[((size_t)s * 386 + 384) * 128 + t]
                + g1 * euW0[((size_t)s * 386 + 385) * 128 + t];
            nu_eff[s * 128 + t] = nub0[s * 128 + t]
                + g0 * nuW0[((size_t)s * 258 + 256) * 128 + t]
                + g1 * nuW0[((size_t)s * 258 + 257) * 128 + t];
        }
    }
}

__global__ __launch_bounds__(256) void zero_kernel(float4* p, int n4) {
    int i = blockIdx.x * 256 + threadIdx.x;
    if (i < n4) p[i] = float4{0.0f, 0.0f, 0.0f, 0.0f};
}

// ---------------- fused MLP2, barrier-free ----------------
// MODE 0: embed nodes  (K1=32, raw 7)  fp32 in  -> fp32 nh
// MODE 1: embed edges  (K1=32, raw 3)  fp32 in  -> bf16 eh
// MODE 2: edge update  (K1=384) bf16 eh + fp32 nh gather -> bf16 eh in-place,
//         atomicAdd fp32 recv, skip+LN
// MODE 3: node update  (K1=256) fp32 nh + fp32 recv -> fp32 nh in-place, skip+LN
// MODE 4: decode GEMM1 only -> fp32 hid (gelu'd)
template <int MODE, int K1, int RAWF>
__global__ __launch_bounds__(256) void mlp2_kernel(
    const void* __restrict__ Araw0v, const float* __restrict__ Araw1,
    const int* __restrict__ senders, const int* __restrict__ receivers,
    const bf16* __restrict__ W0p, const float* __restrict__ b0,
    const bf16* __restrict__ W1p, const float* __restrict__ b1,
    const float* __restrict__ ln_s, const float* __restrict__ ln_b,
    void* out0v, float* recv_out, int Mtotal)
{
    // wave-private hidden round-trip slab (C-layout -> A-layout transpose)
    __shared__ __align__(16) bf16 Hsep[(MODE == 4) ? 1 : (4 * 16 * 136)];

    const int tid = threadIdx.x;
    const int lane = tid & 63;
    const int w = tid >> 6;
    const int n16 = lane & 15;
    const int quad = lane >> 4;
    const int m0 = blockIdx.x * 64;

    const float* Araw0f = (const float*)Araw0v;
    const bf16*  Araw0b = (const bf16*)Araw0v;
    float* out0f = (float*)out0v;
    bf16*  out0b = (bf16*)out0v;

    // this lane's A-row (clamped for loads; stores guarded later)
    int m = m0 + w * 16 + n16;
    if (m >= Mtotal) m = Mtotal - 1;

    int sIdx = 0, rIdx = 0;
    if constexpr (MODE == 2) { sIdx = senders[m]; rIdx = receivers[m]; }

    const f32x4 z = {0.0f, 0.0f, 0.0f, 0.0f};
    f32x4 acc[8];
#pragma unroll
    for (int t = 0; t < 8; ++t) acc[t] = z;

    // ---- GEMM1: [64,K1] @ [K1,128], A-fragments straight from global ----
#pragma unroll
    for (int c = 0; c < K1 / 32; ++c) {
        const int k0 = c * 32 + quad * 8;
        bf16x8 a;
        if constexpr (MODE == 2) {
            if (c < 4)      a = *(const bf16x8*)(Araw0b + (size_t)m * 128 + k0);
            else if (c < 8) a = cvt8(Araw1 + (size_t)sIdx * 128 + (k0 - 128));
            else            a = cvt8(Araw1 + (size_t)rIdx * 128 + (k0 - 256));
        } else if constexpr (MODE == 3) {
            if (c < 4) a = cvt8(Araw0f + (size_t)m * 128 + k0);
            else       a = cvt8(Araw1 + (size_t)m * 128 + (k0 - 128));
        } else if constexpr (MODE == 4) {
            a = cvt8(Araw0f + (size_t)m * 128 + k0);
        } else {  // MODE 0/1: RAWF raw features (<8), only quad 0 nonzero
#pragma unroll
            for (int j = 0; j < 8; ++j) a[j] = (bf16)0.0f;
            if (quad == 0) {
#pragma unroll
                for (int j = 0; j < RAWF; ++j)
                    a[j] = (bf16)Araw0f[(size_t)m * RAWF + j];
            }
        }
        const bf16* bp = W0p + ((size_t)((c * 4 + quad) * 128 + n16)) * 8;
#pragma unroll
        for (int t = 0; t < 8; ++t) {
            bf16x8 b = *(const bf16x8*)(bp + t * 128);
            acc[t] = __builtin_amdgcn_mfma_f32_16x16x32_bf16(a, b, acc[t], 0, 0, 0);
        }
    }

    float b0v[8];
#pragma unroll
    for (int t = 0; t < 8; ++t) b0v[t] = b0[t * 16 + n16];

    if constexpr (MODE == 4) {  // decode layer 1 only
#pragma unroll
        for (int t = 0; t < 8; ++t)
#pragma unroll
            for (int r = 0; r < 4; ++r) {
                int row = m0 + w * 16 + quad * 4 + r;
                if (row < Mtotal)
                    out0f[(size_t)row * 128 + t * 16 + n16] = gelu_t(acc[t][r] + b0v[t]);
            }
        return;
    }

    // hidden -> A-operand layout via wave-private LDS slab (no barrier needed)
    bf16* Hw = &Hsep[w * 16 * 136];
#pragma unroll
    for (int t = 0; t < 8; ++t)
#pragma unroll
        for (int r = 0; r < 4; ++r)
            Hw[(quad * 4 + r) * 136 + t * 16 + n16] = (bf16)gelu_t(acc[t][r] + b0v[t]);

    f32x4 acc2[8];
#pragma unroll
    for (int t = 0; t < 8; ++t) acc2[t] = z;

    // ---- GEMM2: [64,128] @ [128,128] ----
#pragma unroll
    for (int kc = 0; kc < 128; kc += 32) {
        bf16x8 a = *(const bf16x8*)&Hw[n16 * 136 + kc + quad * 8];
        const bf16* bp = W1p + ((size_t)(((kc >> 3) + quad) * 128 + n16)) * 8;
#pragma unroll
        for (int t = 0; t < 8; ++t) {
            bf16x8 b = *(const bf16x8*)(bp + t * 128);
            acc2[t] = __builtin_amdgcn_mfma_f32_16x16x32_bf16(a, b, acc2[t], 0, 0, 0);
        }
    }

    if constexpr (MODE == 0 || MODE == 1) {  // embed: plain store
#pragma unroll
        for (int t = 0; t < 8; ++t) {
            float b1v = b1[t * 16 + n16];
#pragma unroll
            for (int r = 0; r < 4; ++r) {
                int row = m0 + w * 16 + quad * 4 + r;
                if (row < Mtotal) {
                    float v = acc2[t][r] + b1v;
                    if constexpr (MODE == 0) out0f[(size_t)row * 128 + t * 16 + n16] = v;
                    else                     out0b[(size_t)row * 128 + t * 16 + n16] = (bf16)v;
                }
            }
        }
        return;
    }

    // ---- MODE 2/3 epilogue: (atomic scatter) + skip + LayerNorm ----
    float b1v[8], scl[8], bia[8];
#pragma unroll
    for (int t = 0; t < 8; ++t) {
        int col = t * 16 + n16;
        b1v[t] = b1[col]; scl[t] = ln_s[col]; bia[t] = ln_b[col];
    }
    int rowg[4], rcv4[4];
#pragma unroll
    for (int r = 0; r < 4; ++r) {
        rowg[r] = m0 + w * 16 + quad * 4 + r;
        if constexpr (MODE == 2) rcv4[r] = __shfl(rIdx, quad * 4 + r);  // lane with n16==quad*4+r
    }
    float x[8][4];
    float sm[4] = {0, 0, 0, 0}, sq[4] = {0, 0, 0, 0};
#pragma unroll
    for (int t = 0; t < 8; ++t) {
        int col = t * 16 + n16;
#pragma unroll
        for (int r = 0; r < 4; ++r) {
            float v = acc2[t][r] + b1v[t];
            bool ok = rowg[r] < Mtotal;
            float old;
            if constexpr (MODE == 2) {
                if (ok) unsafeAtomicAdd(recv_out + (size_t)rcv4[r] * 128 + col, v);
                old = ok ? (float)Araw0b[(size_t)rowg[r] * 128 + col] : 0.0f;
            } else {
                old = ok ? Araw0f[(size_t)rowg[r] * 128 + col] : 0.0f;
            }
            float xx = old + v;
            x[t][r] = xx; sm[r] += xx; sq[r] += xx * xx;
        }
    }
    // row lives entirely in this 16-lane quad: butterfly over masks 1,2,4,8
#pragma unroll
    for (int mm = 1; mm < 16; mm <<= 1) {
#pragma unroll
        for (int r = 0; r < 4; ++r) {
            sm[r] += __shfl_xor(sm[r], mm);
            sq[r] += __shfl_xor(sq[r], mm);
        }
    }
    float mean[4], inv[4];
#pragma unroll
    for (int r = 0; r < 4; ++r) {
        mean[r] = sm[r] * (1.0f / 128.0f);
        float var = sq[r] * (1.0f / 128.0f) - mean[r] * mean[r];
        inv[r] = rsqrtf(var + 1e-6f);
    }
#pragma unroll
    for (int t = 0; t < 8; ++t)
#pragma unroll
        for (int r = 0; r < 4; ++r)
            if (rowg[r] < Mtotal) {
                float v = (x[t][r] - mean[r]) * inv[r] * scl[t] + bia[t];
                if constexpr (MODE == 2) out0b[(size_t)rowg[r] * 128 + t * 16 + n16] = (bf16)v;
                else                     out0f[(size_t)rowg[r] * 128 + t * 16 + n16] = v;
            }
}

// ---------------- decoder layer 2: [N,128]@[128,3] ----------------
__global__ __launch_bounds__(256) void decode2_kernel(
    const float* __restrict__ hid, const float* __restrict__ W1,
    const float* __restrict__ b1, float* __restrict__ out, int n)
{
    int gid = blockIdx.x * 256 + threadIdx.x;
    if (gid >= n * 3) return;
    int node = gid / 3, o = gid - node * 3;
    const float* h = hid + (size_t)node * 128;
    float s = b1[o];
#pragma unroll 8
    for (int k = 0; k < 128; ++k) s += h[k] * W1[k * 3 + o];
    out[gid] = s;
}

extern "C" void kernel_launch(void* const* d_in, const int* in_sizes, int n_in,
                              void* d_out, int out_size, void* d_ws, size_t ws_size,
                              hipStream_t stream) {
    const float* nodes   = (const float*)d_in[0];
    const float* edges   = (const float*)d_in[1];
    const float* glob    = (const float*)d_in[2];
    const int*   senders = (const int*)d_in[3];
    const int*   recvrs  = (const int*)d_in[4];
    const float* ne_W0 = (const float*)d_in[5],  *ne_b0 = (const float*)d_in[6];
    const float* ne_W1 = (const float*)d_in[7],  *ne_b1 = (const float*)d_in[8];
    const float* ee_W0 = (const float*)d_in[9],  *ee_b0 = (const float*)d_in[10];
    const float* ee_W1 = (const float*)d_in[11], *ee_b1 = (const float*)d_in[12];
    const float* eu_W0 = (const float*)d_in[13], *eu_b0 = (const float*)d_in[14];
    const float* eu_W1 = (const float*)d_in[15], *eu_b1 = (const float*)d_in[16];
    const float* nu_W0 = (const float*)d_in[17], *nu_b0 = (const float*)d_in[18];
    const float* nu_W1 = (const float*)d_in[19], *nu_b1 = (const float*)d_in[20];
    const float* ln_s  = (const float*)d_in[21], *ln_b  = (const float*)d_in[22];
    const float* dc_W0 = (const float*)d_in[23], *dc_b0 = (const float*)d_in[24];
    const float* dc_W1 = (const float*)d_in[25], *dc_b1 = (const float*)d_in[26];

    const int N = 50000, E = 500000;

    const int KD[13] = {32, 128, 32, 128, 384, 384, 128, 128, 256, 256, 128, 128, 128};
    const int KC[13] = {7, 128, 3, 128, 384, 384, 128, 128, 256, 256, 128, 128, 128};
    int pre[14]; pre[0] = 0;
    for (int i = 0; i < 13; ++i) pre[i + 1] = pre[i] + KD[i] * 128;
    const int totalPack = pre[13];  // 286720 elems

    char* ws = (char*)d_ws;
    size_t off = 0;
    auto alloc = [&](size_t bytes) -> char* {
        char* p = ws + off;
        off = (off + bytes + 255) & ~(size_t)255;
        return p;
    };
    bf16*  Wp     = (bf16*)alloc((size_t)totalPack * 2);
    float* b0e_eu = (float*)alloc(2 * 128 * 4);
    float* b0e_nu = (float*)alloc(2 * 128 * 4);
    float* nh     = (float*)alloc((size_t)N * 128 * 4);
    float* recvb  = (float*)alloc((size_t)N * 128 * 4);
    bf16*  eh     = (bf16*)alloc((size_t)E * 128 * 2);
    float* hid    = recvb;  // reuse: received dead after last node update

    if (off > ws_size) return;  // clean diagnostic instead of OOB fault

    PackArgs pa;
    const float* srcs[13] = {
        ne_W0, ne_W1, ee_W0, ee_W1,
        eu_W0, eu_W0 + (size_t)386 * 128,
        eu_W1, eu_W1 + (size_t)128 * 128,
        nu_W0, nu_W0 + (size_t)258 * 128,
        nu_W1, nu_W1 + (size_t)128 * 128,
        dc_W0};
    for (int i = 0; i < 13; ++i) { pa.d[i].src = srcs[i]; pa.d[i].Kcopy = KC[i]; pa.d[i].dstOff = pre[i]; }

    pack_all_kernel<<<(totalPack + 255) / 256, 256, 0, stream>>>(pa, Wp, totalPack);
    fold_bias_kernel<<<1, 128, 0, stream>>>(glob, eu_W0, eu_b0, nu_W0, nu_b0, b0e_eu, b0e_nu);

    const int gN = (N + 63) / 64, gE = (E + 63) / 64;
    mlp2_kernel<0, 32, 7><<<gN, 256, 0, stream>>>(
        nodes, nullptr, nullptr, nullptr, Wp + pre[0], ne_b0, Wp + pre[1], ne_b1,
        nullptr, nullptr, nh, nullptr, N);
    mlp2_kernel<1, 32, 3><<<gE, 256, 0, stream>>>(
        edges, nullptr, nullptr, nullptr, Wp + pre[2], ee_b0, Wp + pre[3], ee_b1,
        nullptr, nullptr, eh, nullptr, E);

    const int n4 = N * 128 / 4;
    for (int s = 0; s < 2; ++s) {
        zero_kernel<<<(n4 + 255) / 256, 256, 0, stream>>>((float4*)recvb, n4);
        mlp2_kernel<2, 384, 0><<<gE, 256, 0, stream>>>(
            eh, nh, senders, recvrs, Wp + pre[4 + s], b0e_eu + s * 128,
            Wp + pre[6 + s], eu_b1 + s * 128, ln_s, ln_b, eh, recvb, E);
        mlp2_kernel<3, 256, 0><<<gN, 256, 0, stream>>>(
            nh, recvb, nullptr, nullptr, Wp + pre[8 + s], b0e_nu + s * 128,
            Wp + pre[10 + s], nu_b1 + s * 128, ln_s, ln_b, nh, nullptr, N);
    }

    mlp2_kernel<4, 128, 0><<<gN, 256, 0, stream>>>(
        nh, nullptr, nullptr, nullptr, Wp + pre[12], dc_b0, nullptr, nullptr,
        nullptr, nullptr, hid, nullptr, N);
    decode2_kernel<<<(N * 3 + 255) / 256, 256, 0, stream>>>(hid, dc_W1, dc_b1, (float*)d_out, N);
}

// Round 4
// 1003.210 us; speedup vs baseline: 1.5682x; 1.4510x over previous
//
#include <hip/hip_runtime.h>
#include <hip/hip_bf16.h>

// GraphConvNet on MI355X — round 3: receiver-sorted edges + run-length-reduced
// atomics + bf16 node state + accumulator reuse.
// Round-3 changes vs round 2 (MODE2 585 us, all pipes idle, occ 33% reg-bound):
//   * edges permuted into receiver-sorted order once per launch
//     (hist -> single-block scan -> scatter). Sorted => MFMA-quad rows mostly
//     share a receiver => in-register run-reduce => ~3x fewer atomics (64M->21M)
//   * nh kept ONLY as bf16 mirror: all A-fragments incl. gathers are bf16x8
//     16B loads (no fp32 cvt), saves 25.6 MB ws
//   * GEMM2 reuses GEMM1 accumulators (saves 32 AGPRs) + launch_bounds(256,4)
//     => target 4 waves/SIMD (occ 33% -> ~50%)
// ws footprint ~172 MB (known-good envelope: 180 MB passed in r1/r2).
//
// MFMA fragment facts (guide §3, m89/m91/m120 verified):
//   A: lane holds A[m=lane&15][k=(lane>>4)*8+j]
//   B: lane holds B[k=(lane>>4)*8+j][n=lane&15]
//   C/D: lane reg r holds C[row=(lane>>4)*4+r][col=lane&15]

typedef __bf16 bf16;
typedef __attribute__((ext_vector_type(8))) __bf16 bf16x8;
typedef __attribute__((ext_vector_type(4))) float f32x4;

__device__ __forceinline__ float gelu_t(float x) {
    const float c0 = 0.7978845608028654f;
    float u = c0 * (x + 0.044715f * x * x * x);
    float au = fabsf(u);
    float e = __expf(-2.0f * au);
    float t = (1.0f - e) / (1.0f + e);
    t = (u < 0.0f) ? -t : t;
    return 0.5f * x * (1.0f + t);
}

__device__ __forceinline__ bf16x8 cvt8(const float* __restrict__ p) {
    float4 v0 = *(const float4*)p;
    float4 v1 = *(const float4*)(p + 4);
    bf16x8 a;
    a[0] = (bf16)v0.x; a[1] = (bf16)v0.y; a[2] = (bf16)v0.z; a[3] = (bf16)v0.w;
    a[4] = (bf16)v1.x; a[5] = (bf16)v1.y; a[6] = (bf16)v1.z; a[7] = (bf16)v1.w;
    return a;
}

// ---------------- weight packing: [K,128] fp32 -> bf16 [K/8][128][8] ----------------
struct PackDesc { const float* src; int Kcopy; int dstOff; };
struct PackArgs { PackDesc d[13]; };

__global__ __launch_bounds__(256) void pack_all_kernel(PackArgs pa, bf16* dst, int total) {
    int i = blockIdx.x * 256 + threadIdx.x;
    if (i >= total) return;
    int s = 0;
#pragma unroll
    for (int j = 1; j < 13; ++j) if (i >= pa.d[j].dstOff) s = j;
    int local = i - pa.d[s].dstOff;
    int k = local >> 7, n = local & 127;
    float v = (k < pa.d[s].Kcopy) ? pa.d[s].src[(size_t)k * 128 + n] : 0.0f;
    dst[pa.d[s].dstOff + ((k >> 3) * 128 + n) * 8 + (k & 7)] = (bf16)v;
}

__global__ void fold_bias_kernel(const float* g, const float* euW0, const float* eub0,
                                 const float* nuW0, const float* nub0,
                                 float* eu_eff, float* nu_eff) {
    int t = threadIdx.x;
    if (t < 128) {
        float g0 = g[0], g1 = g[1];
#pragma unroll
        for (int s = 0; s < 2; ++s) {
            eu_eff[s * 128 + t] = eub0[s * 128 + t]
                + g0 * euW0[((size_t)s * 386 + 384) * 128 + t]
                + g1 * euW0[((size_t)s * 386 + 385) * 128 + t];
            nu_eff[s * 128 + t] = nub0[s * 128 + t]
                + g0 * nuW0[((size_t)s * 258 + 256) * 128 + t]
                + g1 * nuW0[((size_t)s * 258 + 257) * 128 + t];
        }
    }
}

__global__ __launch_bounds__(256) void zero_kernel(float4* p, int n4) {
    int i = blockIdx.x * 256 + threadIdx.x;
    if (i < n4) p[i] = float4{0.0f, 0.0f, 0.0f, 0.0f};
}

// ---------------- receiver-sort (counting sort) ----------------
__global__ __launch_bounds__(256) void hist_kernel(const int* __restrict__ recv,
                                                   int* __restrict__ deg, int E) {
    int e = blockIdx.x * 256 + threadIdx.x;
    if (e < E) atomicAdd(&deg[recv[e]], 1);
}

// single-workgroup exclusive scan of deg[0..n) -> cursor
__global__ __launch_bounds__(256) void scan_kernel(const int* __restrict__ deg,
                                                   int* __restrict__ cursor, int n) {
    __shared__ int part[256];
    __shared__ int base[256];
    int t = threadIdx.x;
    int chunk = (n + 255) / 256;
    int s0 = t * chunk, s1 = min(s0 + chunk, n);
    int s = 0;
    for (int i = s0; i < s1; ++i) s += deg[i];
    part[t] = s;
    __syncthreads();
    if (t == 0) { int a = 0; for (int i = 0; i < 256; ++i) { base[i] = a; a += part[i]; } }
    __syncthreads();
    int a = base[t];
    for (int i = s0; i < s1; ++i) { cursor[i] = a; a += deg[i]; }
}

__global__ __launch_bounds__(256) void scatter_kernel(
    const int* __restrict__ send, const int* __restrict__ recv, int* __restrict__ cursor,
    int* __restrict__ eperm, int* __restrict__ sendp, int* __restrict__ recvp, int E) {
    int e = blockIdx.x * 256 + threadIdx.x;
    if (e >= E) return;
    int r = recv[e];
    int pos = atomicAdd(&cursor[r], 1);
    eperm[pos] = e; sendp[pos] = send[e]; recvp[pos] = r;
}

// ---------------- fused MLP2, barrier-free ----------------
// MODE 0: embed nodes  (K1=32, raw 7)  fp32 in  -> bf16 nh_b
// MODE 1: embed edges  (K1=32, raw 3)  fp32 in (via eperm) -> bf16 eh (sorted order)
// MODE 2: edge update  (K1=384) bf16 eh + bf16 nh_b gather -> bf16 eh in-place,
//         run-reduced atomicAdd into fp32 recv, skip+LN
// MODE 3: node update  (K1=256) bf16 nh_b + fp32 recv -> bf16 nh_b in-place, skip+LN
// MODE 4: decode GEMM1 only: bf16 nh_b -> fp32 hid (gelu'd)
template <int MODE, int K1, int RAWF>
__global__ __launch_bounds__(256, 4) void mlp2_kernel(
    const void* __restrict__ Araw0v, const void* __restrict__ Araw1v,
    const int* __restrict__ sendp, const int* __restrict__ recvp,
    const bf16* __restrict__ W0p, const float* __restrict__ b0,
    const bf16* __restrict__ W1p, const float* __restrict__ b1,
    const float* __restrict__ ln_s, const float* __restrict__ ln_b,
    void* out0v, float* recv_out, int Mtotal)
{
    // wave-private hidden round-trip slab (C-layout -> A-layout transpose)
    __shared__ __align__(16) bf16 Hsep[(MODE == 4) ? 1 : (4 * 16 * 136)];

    const int tid = threadIdx.x;
    const int lane = tid & 63;
    const int w = tid >> 6;
    const int n16 = lane & 15;
    const int quad = lane >> 4;
    const int m0 = blockIdx.x * 64;

    const float* Araw0f = (const float*)Araw0v;
    const bf16*  Araw0b = (const bf16*)Araw0v;
    const bf16*  Araw1b = (const bf16*)Araw1v;
    const float* Araw1f = (const float*)Araw1v;
    float* out0f = (float*)out0v;
    bf16*  out0b = (bf16*)out0v;

    // this lane's A-row (clamped for loads; stores guarded later)
    int m = m0 + w * 16 + n16;
    if (m >= Mtotal) m = Mtotal - 1;

    int sIdx = 0, rIdx = 0;
    if constexpr (MODE == 2) { sIdx = sendp[m]; rIdx = recvp[m]; }
    int permIdx = 0;
    if constexpr (MODE == 1) permIdx = sendp[m];  // eperm passed via sendp slot

    const f32x4 z = {0.0f, 0.0f, 0.0f, 0.0f};
    f32x4 acc[8];
#pragma unroll
    for (int t = 0; t < 8; ++t) acc[t] = z;

    // ---- GEMM1: [64,K1] @ [K1,128], A-fragments straight from global ----
#pragma unroll
    for (int c = 0; c < K1 / 32; ++c) {
        const int k0 = c * 32 + quad * 8;
        bf16x8 a;
        if constexpr (MODE == 2) {
            if (c < 4)      a = *(const bf16x8*)(Araw0b + (size_t)m * 128 + k0);
            else if (c < 8) a = *(const bf16x8*)(Araw1b + (size_t)sIdx * 128 + (k0 - 128));
            else            a = *(const bf16x8*)(Araw1b + (size_t)rIdx * 128 + (k0 - 256));
        } else if constexpr (MODE == 3) {
            if (c < 4) a = *(const bf16x8*)(Araw0b + (size_t)m * 128 + k0);
            else       a = cvt8(Araw1f + (size_t)m * 128 + (k0 - 128));
        } else if constexpr (MODE == 4) {
            a = *(const bf16x8*)(Araw0b + (size_t)m * 128 + k0);
        } else {  // MODE 0/1: RAWF raw features (<8), only quad 0 nonzero
#pragma unroll
            for (int j = 0; j < 8; ++j) a[j] = (bf16)0.0f;
            if (quad == 0) {
                int srcRow = (MODE == 1) ? permIdx : m;
#pragma unroll
                for (int j = 0; j < RAWF; ++j)
                    a[j] = (bf16)Araw0f[(size_t)srcRow * RAWF + j];
            }
        }
        const bf16* bp = W0p + ((size_t)((c * 4 + quad) * 128 + n16)) * 8;
#pragma unroll
        for (int t = 0; t < 8; ++t) {
            bf16x8 b = *(const bf16x8*)(bp + t * 128);
            acc[t] = __builtin_amdgcn_mfma_f32_16x16x32_bf16(a, b, acc[t], 0, 0, 0);
        }
    }

    float b0v[8];
#pragma unroll
    for (int t = 0; t < 8; ++t) b0v[t] = b0[t * 16 + n16];

    if constexpr (MODE == 4) {  // decode layer 1 only
#pragma unroll
        for (int t = 0; t < 8; ++t)
#pragma unroll
            for (int r = 0; r < 4; ++r) {
                int row = m0 + w * 16 + quad * 4 + r;
                if (row < Mtotal)
                    out0f[(size_t)row * 128 + t * 16 + n16] = gelu_t(acc[t][r] + b0v[t]);
            }
        return;
    }

    // hidden -> A-operand layout via wave-private LDS slab (no barrier needed)
    bf16* Hw = &Hsep[w * 16 * 136];
#pragma unroll
    for (int t = 0; t < 8; ++t)
#pragma unroll
        for (int r = 0; r < 4; ++r)
            Hw[(quad * 4 + r) * 136 + t * 16 + n16] = (bf16)gelu_t(acc[t][r] + b0v[t]);

    // ---- GEMM2: [64,128] @ [128,128] — REUSE acc (saves 32 AGPRs) ----
#pragma unroll
    for (int t = 0; t < 8; ++t) acc[t] = z;
#pragma unroll
    for (int kc = 0; kc < 128; kc += 32) {
        bf16x8 a = *(const bf16x8*)&Hw[n16 * 136 + kc + quad * 8];
        const bf16* bp = W1p + ((size_t)(((kc >> 3) + quad) * 128 + n16)) * 8;
#pragma unroll
        for (int t = 0; t < 8; ++t) {
            bf16x8 b = *(const bf16x8*)(bp + t * 128);
            acc[t] = __builtin_amdgcn_mfma_f32_16x16x32_bf16(a, b, acc[t], 0, 0, 0);
        }
    }

    if constexpr (MODE == 0 || MODE == 1) {  // embed: plain bf16 store
#pragma unroll
        for (int t = 0; t < 8; ++t) {
            float b1v = b1[t * 16 + n16];
#pragma unroll
            for (int r = 0; r < 4; ++r) {
                int row = m0 + w * 16 + quad * 4 + r;
                if (row < Mtotal)
                    out0b[(size_t)row * 128 + t * 16 + n16] = (bf16)(acc[t][r] + b1v);
            }
        }
        return;
    }

    // ---- MODE 2/3 epilogue: (run-reduced atomic scatter) + skip + LayerNorm ----
    float b1v[8], scl[8], bia[8];
#pragma unroll
    for (int t = 0; t < 8; ++t) {
        int col = t * 16 + n16;
        b1v[t] = b1[col]; scl[t] = ln_s[col]; bia[t] = ln_b[col];
    }
    int rowg[4], rcv4[4];
#pragma unroll
    for (int r = 0; r < 4; ++r) {
        rowg[r] = m0 + w * 16 + quad * 4 + r;
        if constexpr (MODE == 2) rcv4[r] = __shfl(rIdx, quad * 4 + r);  // wave rows 0..15 live in lanes 0..15
    }
    float x[8][4];
    float sm[4] = {0, 0, 0, 0}, sq[4] = {0, 0, 0, 0};
#pragma unroll
    for (int t = 0; t < 8; ++t) {
        int col = t * 16 + n16;
        float run = 0.0f;  // MODE2: running per-receiver partial (receiver-sorted rows)
#pragma unroll
        for (int r = 0; r < 4; ++r) {
            bool ok = rowg[r] < Mtotal;
            float v = ok ? (acc[t][r] + b1v[t]) : 0.0f;
            if constexpr (MODE == 2) {
                if (r == 0) run = v;
                else {
                    if (rcv4[r] == rcv4[r - 1]) run += v;
                    else {
                        unsafeAtomicAdd(recv_out + (size_t)rcv4[r - 1] * 128 + col, run);
                        run = v;
                    }
                }
            }
            float old = ok ? (float)Araw0b[(size_t)rowg[r] * 128 + col] : 0.0f;
            float xx = old + v;
            x[t][r] = xx; sm[r] += xx; sq[r] += xx * xx;
        }
        if constexpr (MODE == 2)
            unsafeAtomicAdd(recv_out + (size_t)rcv4[3] * 128 + col, run);
    }
    // row lives entirely in this 16-lane quad: butterfly over masks 1,2,4,8
#pragma unroll
    for (int mm = 1; mm < 16; mm <<= 1) {
#pragma unroll
        for (int r = 0; r < 4; ++r) {
            sm[r] += __shfl_xor(sm[r], mm);
            sq[r] += __shfl_xor(sq[r], mm);
        }
    }
    float mean[4], inv[4];
#pragma unroll
    for (int r = 0; r < 4; ++r) {
        mean[r] = sm[r] * (1.0f / 128.0f);
        float var = sq[r] * (1.0f / 128.0f) - mean[r] * mean[r];
        inv[r] = rsqrtf(var + 1e-6f);
    }
#pragma unroll
    for (int t = 0; t < 8; ++t)
#pragma unroll
        for (int r = 0; r < 4; ++r)
            if (rowg[r] < Mtotal)
                out0b[(size_t)rowg[r] * 128 + t * 16 + n16] =
                    (bf16)((x[t][r] - mean[r]) * inv[r] * scl[t] + bia[t]);
}

// ---------------- decoder layer 2: [N,128]@[128,3] ----------------
__global__ __launch_bounds__(256) void decode2_kernel(
    const float* __restrict__ hid, const float* __restrict__ W1,
    const float* __restrict__ b1, float* __restrict__ out, int n)
{
    int gid = blockIdx.x * 256 + threadIdx.x;
    if (gid >= n * 3) return;
    int node = gid / 3, o = gid - node * 3;
    const float* h = hid + (size_t)node * 128;
    float s = b1[o];
#pragma unroll 8
    for (int k = 0; k < 128; ++k) s += h[k] * W1[k * 3 + o];
    out[gid] = s;
}

extern "C" void kernel_launch(void* const* d_in, const int* in_sizes, int n_in,
                              void* d_out, int out_size, void* d_ws, size_t ws_size,
                              hipStream_t stream) {
    const float* nodes   = (const float*)d_in[0];
    const float* edges   = (const float*)d_in[1];
    const float* glob    = (const float*)d_in[2];
    const int*   senders = (const int*)d_in[3];
    const int*   recvrs  = (const int*)d_in[4];
    const float* ne_W0 = (const float*)d_in[5],  *ne_b0 = (const float*)d_in[6];
    const float* ne_W1 = (const float*)d_in[7],  *ne_b1 = (const float*)d_in[8];
    const float* ee_W0 = (const float*)d_in[9],  *ee_b0 = (const float*)d_in[10];
    const float* ee_W1 = (const float*)d_in[11], *ee_b1 = (const float*)d_in[12];
    const float* eu_W0 = (const float*)d_in[13], *eu_b0 = (const float*)d_in[14];
    const float* eu_W1 = (const float*)d_in[15], *eu_b1 = (const float*)d_in[16];
    const float* nu_W0 = (const float*)d_in[17], *nu_b0 = (const float*)d_in[18];
    const float* nu_W1 = (const float*)d_in[19], *nu_b1 = (const float*)d_in[20];
    const float* ln_s  = (const float*)d_in[21], *ln_b  = (const float*)d_in[22];
    const float* dc_W0 = (const float*)d_in[23], *dc_b0 = (const float*)d_in[24];
    const float* dc_W1 = (const float*)d_in[25], *dc_b1 = (const float*)d_in[26];

    const int N = 50000, E = 500000;

    const int KD[13] = {32, 128, 32, 128, 384, 384, 128, 128, 256, 256, 128, 128, 128};
    const int KC[13] = {7, 128, 3, 128, 384, 384, 128, 128, 256, 256, 128, 128, 128};
    int pre[14]; pre[0] = 0;
    for (int i = 0; i < 13; ++i) pre[i + 1] = pre[i] + KD[i] * 128;
    const int totalPack = pre[13];

    char* ws = (char*)d_ws;
    size_t off = 0;
    auto alloc = [&](size_t bytes) -> char* {
        char* p = ws + off;
        off = (off + bytes + 255) & ~(size_t)255;
        return p;
    };
    bf16*  Wp     = (bf16*)alloc((size_t)totalPack * 2);
    float* b0e_eu = (float*)alloc(2 * 128 * 4);
    float* b0e_nu = (float*)alloc(2 * 128 * 4);
    bf16*  nh_b   = (bf16*)alloc((size_t)N * 128 * 2);      // 12.8 MB
    float* recvb  = (float*)alloc((size_t)N * 128 * 4);     // 25.6 MB
    bf16*  eh     = (bf16*)alloc((size_t)E * 128 * 2);      // 128 MB
    int*   deg    = (int*)alloc((size_t)N * 4);
    int*   cursor = (int*)alloc((size_t)N * 4);
    int*   eperm  = (int*)alloc((size_t)E * 4);
    int*   sendp  = (int*)alloc((size_t)E * 4);
    int*   recvp  = (int*)alloc((size_t)E * 4);
    float* hid    = recvb;  // reuse: received dead after last node update

    if (off > ws_size) return;  // clean diagnostic instead of OOB fault

    PackArgs pa;
    const float* srcs[13] = {
        ne_W0, ne_W1, ee_W0, ee_W1,
        eu_W0, eu_W0 + (size_t)386 * 128,
        eu_W1, eu_W1 + (size_t)128 * 128,
        nu_W0, nu_W0 + (size_t)258 * 128,
        nu_W1, nu_W1 + (size_t)128 * 128,
        dc_W0};
    for (int i = 0; i < 13; ++i) { pa.d[i].src = srcs[i]; pa.d[i].Kcopy = KC[i]; pa.d[i].dstOff = pre[i]; }

    pack_all_kernel<<<(totalPack + 255) / 256, 256, 0, stream>>>(pa, Wp, totalPack);
    fold_bias_kernel<<<1, 128, 0, stream>>>(glob, eu_W0, eu_b0, nu_W0, nu_b0, b0e_eu, b0e_nu);

    // ---- receiver counting-sort (graph static; rebuilt every launch) ----
    const int gEdge = (E + 255) / 256;
    zero_kernel<<<(N / 4 + 255) / 256, 256, 0, stream>>>((float4*)deg, N / 4);
    hist_kernel<<<gEdge, 256, 0, stream>>>(recvrs, deg, E);
    scan_kernel<<<1, 256, 0, stream>>>(deg, cursor, N);
    scatter_kernel<<<gEdge, 256, 0, stream>>>(senders, recvrs, cursor, eperm, sendp, recvp, E);

    const int gN = (N + 63) / 64, gE = (E + 63) / 64;
    mlp2_kernel<0, 32, 7><<<gN, 256, 0, stream>>>(
        nodes, nullptr, nullptr, nullptr, Wp + pre[0], ne_b0, Wp + pre[1], ne_b1,
        nullptr, nullptr, nh_b, nullptr, N);
    mlp2_kernel<1, 32, 3><<<gE, 256, 0, stream>>>(
        edges, nullptr, eperm, nullptr, Wp + pre[2], ee_b0, Wp + pre[3], ee_b1,
        nullptr, nullptr, eh, nullptr, E);

    const int n4 = N * 128 / 4;
    for (int s = 0; s < 2; ++s) {
        zero_kernel<<<(n4 + 255) / 256, 256, 0, stream>>>((float4*)recvb, n4);
        mlp2_kernel<2, 384, 0><<<gE, 256, 0, stream>>>(
            eh, nh_b, sendp, recvp, Wp + pre[4 + s], b0e_eu + s * 128,
            Wp + pre[6 + s], eu_b1 + s * 128, ln_s, ln_b, eh, recvb, E);
        mlp2_kernel<3, 256, 0><<<gN, 256, 0, stream>>>(
            nh_b, recvb, nullptr, nullptr, Wp + pre[8 + s], b0e_nu + s * 128,
            Wp + pre[10 + s], nu_b1 + s * 128, ln_s, ln_b, nh_b, nullptr, N);
    }

    mlp2_kernel<4, 128, 0><<<gN, 256, 0, stream>>>(
        nh_b, nullptr, nullptr, nullptr, Wp + pre[12], dc_b0, nullptr, nullptr,
        nullptr, nullptr, hid, nullptr, N);
    decode2_kernel<<<(N * 3 + 255) / 256, 256, 0, stream>>>(hid, dc_W1, dc_b1, (float*)d_out, N);
}